// Round 1
// baseline (156.578 us; speedup 1.0000x reference)
//
#include <hip/hip_runtime.h>

// ContrastiveLoss on MI355X (gfx950) — round 5
// loss = (1/n) [ sum_i P_i*(10+log z_i) - 10*(sum_c ||S_c||^2 - n) ]
//   z_i = sum_{j != i} exp(10*dot_ij - 10)
//   S_c = sum_{label_j == c} e_j   (fp32, via class-scan kernel)
// R5: possum is eliminated from the hot loop entirely (algebraic identity:
// sum_i possum_i = sum_c ||S_c||^2 - n). zsum now computes ONLY z:
// no label loads, no pacc, no cmp/cndmask. Raw v_exp_f32 via
// __builtin_amdgcn_exp2f. Explicit register double-buffer prefetch of the
// next B tile hides L2 latency under the MFMA+exp epilogue.

#define N 8192
#define D 128
#define NCLS 100
#define JSPLIT 32          // grid.y; j-window = 256 rows
#define IBLK 256           // i-rows per block (4 waves x 64)
#define NJT ((N / JSPLIT) / 16)
#define SCH 8              // class-scan chunks
#define K2E 14.4269504088896340736f   // 10*log2(e)
#define LN2 0.69314718055994530942f

typedef __bf16 bf16x8 __attribute__((ext_vector_type(8)));
typedef float f32x4 __attribute__((ext_vector_type(4)));

// ws layout (bytes)
#define EBF_OFF 0u          // bf16 E fragment-major: 2 MB
#define INV_OFF 0x200000u   // per-row inverse norm: 32 KB
#define CNT_OFF 0x208000u   // class counts: 512 B (zeroed)
#define Z_OFF   0x208200u   // z per row: 32 KB (zeroed)
#define SP_OFF  0x210200u   // S partials: SCH*100*128*4 = 400 KB (fully written)
#define ZERO_SZ (512u + 32768u)

__device__ __forceinline__ unsigned short f32_to_bf16_rne(float f) {
    unsigned int u = __float_as_uint(f);
    u += 0x7fffu + ((u >> 16) & 1u);
    return (unsigned short)(u >> 16);
}

// Fragment-major layout of E (unchanged from R4, harness-verified):
//   row r: grp=r>>4, col=r&15 ; element k: c=k>>5, q=(k>>3)&3, jj=k&7
//   byte = grp*4096 + c*1024 + q*256 + col*16 + jj*2

// Kernel 1: normalize rows -> fragment-major bf16 E; inv-norm; class histogram.
__global__ __launch_bounds__(256) void prep_kernel(
        const float* __restrict__ emb, const int* __restrict__ labels,
        unsigned char* __restrict__ ebf, int* __restrict__ cnt,
        float* __restrict__ invn) {
    const int wave = threadIdx.x >> 6;
    const int lane = threadIdx.x & 63;
    const int row  = blockIdx.x * 4 + wave;

    const float2 v = *(const float2*)(emb + (size_t)row * D + lane * 2);
    float ss = v.x * v.x + v.y * v.y;
    #pragma unroll
    for (int off = 32; off; off >>= 1) ss += __shfl_xor(ss, off);
    const float inv = 1.0f / fmaxf(sqrtf(ss), 1e-12f);

    const int grp = row >> 4, col = row & 15;
    const int c = lane >> 4, q = (lane >> 2) & 3, j2 = lane & 3;
    unsigned int packed = (unsigned int)f32_to_bf16_rne(v.x * inv) |
                          ((unsigned int)f32_to_bf16_rne(v.y * inv) << 16);
    *(unsigned int*)(ebf + grp * 4096 + c * 1024 + q * 256 + col * 16 + j2 * 4) = packed;

    if (lane == 0) {
        invn[row] = inv;
        atomicAdd(&cnt[labels[row]], 1);
    }
}

// Kernel 2: per-class embedding sums (fp32). Block=(class c, chunk ch),
// 128 threads = one dim each. Uniform branch on wave-uniform label read;
// vector load only on match (~1/NCLS of iterations).
__global__ __launch_bounds__(128) void ssum_kernel(
        const float* __restrict__ emb, const int* __restrict__ labels,
        const float* __restrict__ invn, float* __restrict__ spart) {
    const int c  = blockIdx.x;
    const int ch = blockIdx.y;
    const int d  = threadIdx.x;
    const int r0 = ch * (N / SCH);
    float acc = 0.0f;
    #pragma unroll 4
    for (int r = r0; r < r0 + N / SCH; ++r) {
        if (labels[r] == c)
            acc += emb[(size_t)r * D + d] * invn[r];
    }
    spart[(ch * NCLS + c) * D + d] = acc;
}

// Kernel 3: z only. Block = 4 waves; wave owns 64 i-rows (4 groups of 16).
// grid (N/IBLK, JSPLIT). No LDS, no barriers, no labels. B double-buffered
// in registers: next tile's 4x1KB loads issue before current tile's MFMAs.
__global__ __launch_bounds__(256) void zsum_kernel(
        const unsigned char* __restrict__ ebf, float* __restrict__ z) {
    const int t    = threadIdx.x;
    const int w    = t >> 6;
    const int lane = t & 63;
    const int q    = lane >> 4;
    const int col  = lane & 15;
    const int iw   = blockIdx.x * IBLK + w * 64;
    const int jb   = blockIdx.y * (N / JSPLIT);

    // A fragments: 4 groups x 4 K-chunks, coalesced 1KB loads
    bf16x8 a[4][4];
    #pragma unroll
    for (int g = 0; g < 4; ++g) {
        const unsigned char* ag = ebf + (size_t)(iw / 16 + g) * 4096 + lane * 16;
        #pragma unroll
        for (int c = 0; c < 4; ++c) a[g][c] = *(const bf16x8*)(ag + c * 1024);
    }

    float zacc[4][4] = {{0.f,0.f,0.f,0.f},{0.f,0.f,0.f,0.f},
                        {0.f,0.f,0.f,0.f},{0.f,0.f,0.f,0.f}};

    const unsigned char* bbase = ebf + (size_t)(jb / 16) * 4096 + lane * 16;

    // prologue: load B tile 0
    bf16x8 bc[4];
    #pragma unroll
    for (int c = 0; c < 4; ++c) bc[c] = *(const bf16x8*)(bbase + c * 1024);

    #pragma unroll 2
    for (int jt = 0; jt < NJT; ++jt) {
        const int js = jb + jt * 16;

        // prefetch next B tile (last iter reloads current — harmless, defined)
        const int jn = (jt + 1 < NJT) ? jt + 1 : jt;
        bf16x8 bn[4];
        {
            const unsigned char* bg = bbase + (size_t)jn * 4096;
            #pragma unroll
            for (int c = 0; c < 4; ++c) bn[c] = *(const bf16x8*)(bg + c * 1024);
        }

        #pragma unroll
        for (int g = 0; g < 4; ++g) {
            f32x4 acc = {0.f, 0.f, 0.f, 0.f};
            #pragma unroll
            for (int c = 0; c < 4; ++c)
                acc = __builtin_amdgcn_mfma_f32_16x16x32_bf16(a[g][c], bc[c], acc, 0, 0, 0);
            if (js == iw + g * 16) {                  // wave-uniform diagonal tile
                #pragma unroll
                for (int r = 0; r < 4; ++r)
                    zacc[g][r] += (col == q * 4 + r) ? 0.0f
                        : __builtin_amdgcn_exp2f(fmaf(acc[r], K2E, -K2E));
            } else {
                #pragma unroll
                for (int r = 0; r < 4; ++r)
                    zacc[g][r] += __builtin_amdgcn_exp2f(fmaf(acc[r], K2E, -K2E));
            }
        }

        #pragma unroll
        for (int c = 0; c < 4; ++c) bc[c] = bn[c];
    }

    // per-row reduce across the 16 cols of each quad; atomic merge of partials
    #pragma unroll
    for (int g = 0; g < 4; ++g)
        #pragma unroll
        for (int r = 0; r < 4; ++r) {
            float zv = zacc[g][r];
            zv += __shfl_xor(zv, 1);
            zv += __shfl_xor(zv, 2);
            zv += __shfl_xor(zv, 4);
            zv += __shfl_xor(zv, 8);
            if (col == 0)
                atomicAdd(&z[iw + g * 16 + q * 4 + r], zv);
        }
}

// Kernel 4: single-block epilogue.
// loss = [ sum_i P_i*(10+ln z_i) - 10*sum_k S[k]^2 + 10*N ] / N
__global__ __launch_bounds__(1024) void final_kernel(
        const int* __restrict__ labels, const int* __restrict__ cnt,
        const float* __restrict__ z, const float* __restrict__ spart,
        float* __restrict__ out) {
    __shared__ float part[16];
    const int tid = threadIdx.x;
    float acc = 0.0f;
    #pragma unroll
    for (int k = 0; k < N / 1024; ++k) {
        const int row = k * 1024 + tid;
        const int P = cnt[labels[row]] - 1;
        if (P > 0)
            acc += (float)P * fmaf(LN2, __builtin_amdgcn_logf(z[row]), 10.0f);
    }
    #pragma unroll
    for (int k = 0; k < (NCLS * D + 1023) / 1024; ++k) {
        const int idx = k * 1024 + tid;
        if (idx < NCLS * D) {
            float sv = 0.0f;
            #pragma unroll
            for (int ch = 0; ch < SCH; ++ch) sv += spart[ch * (NCLS * D) + idx];
            acc -= 10.0f * sv * sv;
        }
    }
    #pragma unroll
    for (int off = 32; off; off >>= 1) acc += __shfl_xor(acc, off);
    if ((tid & 63) == 0) part[tid >> 6] = acc;
    __syncthreads();
    if (tid == 0) {
        float tot = 0.0f;
        #pragma unroll
        for (int w = 0; w < 16; ++w) tot += part[w];
        out[0] = (tot + 10.0f * (float)N) * (1.0f / (float)N);
    }
}

extern "C" void kernel_launch(void* const* d_in, const int* in_sizes, int n_in,
                              void* d_out, int out_size, void* d_ws, size_t ws_size,
                              hipStream_t stream) {
    const float* emb  = (const float*)d_in[0];
    const int* labels = (const int*)d_in[1];
    float* out        = (float*)d_out;
    char* ws          = (char*)d_ws;

    unsigned char* ebf = (unsigned char*)(ws + EBF_OFF);
    float* invn        = (float*)(ws + INV_OFF);
    int*   cnt         = (int*)(ws + CNT_OFF);
    float* z           = (float*)(ws + Z_OFF);
    float* spart       = (float*)(ws + SP_OFF);

    hipMemsetAsync(ws + CNT_OFF, 0, ZERO_SZ, stream);

    prep_kernel<<<N / 4, 256, 0, stream>>>(emb, labels, ebf, cnt, invn);
    ssum_kernel<<<dim3(NCLS, SCH), 128, 0, stream>>>(emb, labels, invn, spart);
    zsum_kernel<<<dim3(N / IBLK, JSPLIT), 256, 0, stream>>>(ebf, z);
    final_kernel<<<1, 1024, 0, stream>>>(labels, cnt, z, spart, out);
}

// Round 2
// 123.808 us; speedup vs baseline: 1.2647x; 1.2647x over previous
//
#include <hip/hip_runtime.h>

// ContrastiveLoss on MI355X (gfx950) — round 6
// loss = (1/n) [ sum_i P_i*(10+log z_i) - 10*(sum_c ||S_c||^2 - n) ]
//   z_i = sum_{j != i} exp(10*dot_ij - 10)
//   S_c = sum_{label_j == c} e_j
// R6: ssum_kernel deleted (it was 48us of exposed label-load latency).
// S_c is now scattered from prep_kernel via fp32 global atomics into 8
// contention-splitting partials — the normalized values are already in
// registers there. zsum gets s_setprio around the MFMA cluster (waves are
// independent, attn-like regime where setprio measured +4-7%).

#define N 8192
#define D 128
#define NCLS 100
#define JSPLIT 32          // grid.y; j-window = 256 rows
#define IBLK 256           // i-rows per block (4 waves x 64)
#define NJT ((N / JSPLIT) / 16)
#define NPART 8            // S_c contention-splitting partials
#define K2E 14.4269504088896340736f   // 10*log2(e)
#define LN2 0.69314718055994530942f

typedef __bf16 bf16x8 __attribute__((ext_vector_type(8)));
typedef float f32x4 __attribute__((ext_vector_type(4)));

// ws layout (bytes) — CNT/Z/SP contiguous so one memset zeroes all three
#define EBF_OFF 0u          // bf16 E fragment-major: 2 MB
#define INV_OFF 0x200000u   // (spare) 32 KB
#define CNT_OFF 0x208000u   // class counts: 512 B
#define Z_OFF   0x208200u   // z per row: 32 KB
#define SP_OFF  0x210200u   // S partials: NPART*100*128*4 = 400 KB
#define ZERO_SZ (512u + 32768u + (NPART * NCLS * D * 4u))

__device__ __forceinline__ unsigned short f32_to_bf16_rne(float f) {
    unsigned int u = __float_as_uint(f);
    u += 0x7fffu + ((u >> 16) & 1u);
    return (unsigned short)(u >> 16);
}

// Fragment-major layout of E (harness-verified):
//   row r: grp=r>>4, col=r&15 ; element k: c=k>>5, q=(k>>3)&3, jj=k&7
//   byte = grp*4096 + c*1024 + q*256 + col*16 + jj*2

// Kernel 1: normalize rows -> fragment-major bf16 E; class histogram;
// scatter normalized fp32 values into S_c partials (atomics).
__global__ __launch_bounds__(256) void prep_kernel(
        const float* __restrict__ emb, const int* __restrict__ labels,
        unsigned char* __restrict__ ebf, int* __restrict__ cnt,
        float* __restrict__ spart) {
    const int wave = threadIdx.x >> 6;
    const int lane = threadIdx.x & 63;
    const int row  = blockIdx.x * 4 + wave;

    const float2 v = *(const float2*)(emb + (size_t)row * D + lane * 2);
    float ss = v.x * v.x + v.y * v.y;
    #pragma unroll
    for (int off = 32; off; off >>= 1) ss += __shfl_xor(ss, off);
    const float inv = 1.0f / fmaxf(sqrtf(ss), 1e-12f);
    const float ex = v.x * inv, ey = v.y * inv;

    const int grp = row >> 4, col = row & 15;
    const int c = lane >> 4, q = (lane >> 2) & 3, j2 = lane & 3;
    unsigned int packed = (unsigned int)f32_to_bf16_rne(ex) |
                          ((unsigned int)f32_to_bf16_rne(ey) << 16);
    *(unsigned int*)(ebf + grp * 4096 + c * 1024 + q * 256 + col * 16 + j2 * 4) = packed;

    const int lab = labels[row];                      // wave-uniform
    float* sp = spart + (size_t)(row & (NPART - 1)) * (NCLS * D)
                      + (size_t)lab * D + lane * 2;
    atomicAdd(sp, ex);
    atomicAdd(sp + 1, ey);

    if (lane == 0) atomicAdd(&cnt[lab], 1);
}

// Kernel 2: z only. Block = 4 waves; wave owns 64 i-rows (4 groups of 16).
// grid (N/IBLK, JSPLIT). No LDS, no barriers, no labels. B double-buffered
// in registers: next tile's 4x1KB loads issue before current tile's MFMAs.
__global__ __launch_bounds__(256) void zsum_kernel(
        const unsigned char* __restrict__ ebf, float* __restrict__ z) {
    const int t    = threadIdx.x;
    const int w    = t >> 6;
    const int lane = t & 63;
    const int q    = lane >> 4;
    const int col  = lane & 15;
    const int iw   = blockIdx.x * IBLK + w * 64;
    const int jb   = blockIdx.y * (N / JSPLIT);

    // A fragments: 4 groups x 4 K-chunks, coalesced 1KB loads
    bf16x8 a[4][4];
    #pragma unroll
    for (int g = 0; g < 4; ++g) {
        const unsigned char* ag = ebf + (size_t)(iw / 16 + g) * 4096 + lane * 16;
        #pragma unroll
        for (int c = 0; c < 4; ++c) a[g][c] = *(const bf16x8*)(ag + c * 1024);
    }

    float zacc[4][4] = {{0.f,0.f,0.f,0.f},{0.f,0.f,0.f,0.f},
                        {0.f,0.f,0.f,0.f},{0.f,0.f,0.f,0.f}};

    const unsigned char* bbase = ebf + (size_t)(jb / 16) * 4096 + lane * 16;

    // prologue: load B tile 0
    bf16x8 bc[4];
    #pragma unroll
    for (int c = 0; c < 4; ++c) bc[c] = *(const bf16x8*)(bbase + c * 1024);

    #pragma unroll 2
    for (int jt = 0; jt < NJT; ++jt) {
        const int js = jb + jt * 16;

        // prefetch next B tile (last iter reloads current — harmless, defined)
        const int jn = (jt + 1 < NJT) ? jt + 1 : jt;
        bf16x8 bn[4];
        {
            const unsigned char* bg = bbase + (size_t)jn * 4096;
            #pragma unroll
            for (int c = 0; c < 4; ++c) bn[c] = *(const bf16x8*)(bg + c * 1024);
        }

        #pragma unroll
        for (int g = 0; g < 4; ++g) {
            f32x4 acc = {0.f, 0.f, 0.f, 0.f};
            __builtin_amdgcn_s_setprio(1);
            #pragma unroll
            for (int c = 0; c < 4; ++c)
                acc = __builtin_amdgcn_mfma_f32_16x16x32_bf16(a[g][c], bc[c], acc, 0, 0, 0);
            __builtin_amdgcn_s_setprio(0);
            if (js == iw + g * 16) {                  // wave-uniform diagonal tile
                #pragma unroll
                for (int r = 0; r < 4; ++r)
                    zacc[g][r] += (col == q * 4 + r) ? 0.0f
                        : __builtin_amdgcn_exp2f(fmaf(acc[r], K2E, -K2E));
            } else {
                #pragma unroll
                for (int r = 0; r < 4; ++r)
                    zacc[g][r] += __builtin_amdgcn_exp2f(fmaf(acc[r], K2E, -K2E));
            }
        }

        #pragma unroll
        for (int c = 0; c < 4; ++c) bc[c] = bn[c];
    }

    // per-row reduce across the 16 cols of each quad; atomic merge of partials
    #pragma unroll
    for (int g = 0; g < 4; ++g)
        #pragma unroll
        for (int r = 0; r < 4; ++r) {
            float zv = zacc[g][r];
            zv += __shfl_xor(zv, 1);
            zv += __shfl_xor(zv, 2);
            zv += __shfl_xor(zv, 4);
            zv += __shfl_xor(zv, 8);
            if (col == 0)
                atomicAdd(&z[iw + g * 16 + q * 4 + r], zv);
        }
}

// Kernel 3: single-block epilogue.
// loss = [ sum_i P_i*(10+ln z_i) - 10*sum_k S[k]^2 + 10*N ] / N
__global__ __launch_bounds__(1024) void final_kernel(
        const int* __restrict__ labels, const int* __restrict__ cnt,
        const float* __restrict__ z, const float* __restrict__ spart,
        float* __restrict__ out) {
    __shared__ float part[16];
    const int tid = threadIdx.x;
    float acc = 0.0f;
    #pragma unroll
    for (int k = 0; k < N / 1024; ++k) {
        const int row = k * 1024 + tid;
        const int P = cnt[labels[row]] - 1;
        if (P > 0)
            acc += (float)P * fmaf(LN2, __builtin_amdgcn_logf(z[row]), 10.0f);
    }
    #pragma unroll
    for (int k = 0; k < (NCLS * D + 1023) / 1024; ++k) {
        const int idx = k * 1024 + tid;
        if (idx < NCLS * D) {
            float sv = 0.0f;
            #pragma unroll
            for (int ch = 0; ch < NPART; ++ch) sv += spart[ch * (NCLS * D) + idx];
            acc -= 10.0f * sv * sv;
        }
    }
    #pragma unroll
    for (int off = 32; off; off >>= 1) acc += __shfl_xor(acc, off);
    if ((tid & 63) == 0) part[tid >> 6] = acc;
    __syncthreads();
    if (tid == 0) {
        float tot = 0.0f;
        #pragma unroll
        for (int w = 0; w < 16; ++w) tot += part[w];
        out[0] = (tot + 10.0f * (float)N) * (1.0f / (float)N);
    }
}

extern "C" void kernel_launch(void* const* d_in, const int* in_sizes, int n_in,
                              void* d_out, int out_size, void* d_ws, size_t ws_size,
                              hipStream_t stream) {
    const float* emb  = (const float*)d_in[0];
    const int* labels = (const int*)d_in[1];
    float* out        = (float*)d_out;
    char* ws          = (char*)d_ws;

    unsigned char* ebf = (unsigned char*)(ws + EBF_OFF);
    int*   cnt         = (int*)(ws + CNT_OFF);
    float* z           = (float*)(ws + Z_OFF);
    float* spart       = (float*)(ws + SP_OFF);

    hipMemsetAsync(ws + CNT_OFF, 0, ZERO_SZ, stream);

    prep_kernel<<<N / 4, 256, 0, stream>>>(emb, labels, ebf, cnt, spart);
    zsum_kernel<<<dim3(N / IBLK, JSPLIT), 256, 0, stream>>>(ebf, z);
    final_kernel<<<1, 1024, 0, stream>>>(labels, cnt, z, spart, out);
}